// Round 8
// baseline (400.179 us; speedup 1.0000x reference)
//
#include <hip/hip_runtime.h>
#include <hip/hip_bf16.h>

#define HALF_ROWS 262144
#define TAU 0.04f
#define BT_OFF 1024
#define LIST_OFF (BT_OFF + 320 * 512 * 2)   // 1024 + 327680

typedef __attribute__((ext_vector_type(8))) short s16x8;
typedef __attribute__((ext_vector_type(4))) float f32x4;

__device__ __forceinline__ unsigned short f2bf(float f) {
  union { float f; unsigned u; } v; v.f = f;
  unsigned r = v.u + 0x7fffu + ((v.u >> 16) & 1u);   // RTNE
  return (unsigned short)(r >> 16);
}

#define GLOAD_LDS16(g, p) \
  __builtin_amdgcn_global_load_lds((const __attribute__((address_space(1))) void*)(g), \
                                   (__attribute__((address_space(3))) void*)(p), 16, 0, 0)

// waitcnt+barrier fused so nothing slips between
#define WB(N) asm volatile("s_waitcnt vmcnt(" #N ")\n\ts_barrier" ::: "memory")

// 8 f32 -> one bf16x8 fragment via packed converts (RTNE)
__device__ __forceinline__ s16x8 cvt8(const f32x4& a, const f32x4& b) {
  union { int i[4]; s16x8 v; } u;
  asm("v_cvt_pk_bf16_f32 %0, %1, %2" : "=v"(u.i[0]) : "v"(a[0]), "v"(a[1]));
  asm("v_cvt_pk_bf16_f32 %0, %1, %2" : "=v"(u.i[1]) : "v"(a[2]), "v"(a[3]));
  asm("v_cvt_pk_bf16_f32 %0, %1, %2" : "=v"(u.i[2]) : "v"(b[0]), "v"(b[1]));
  asm("v_cvt_pk_bf16_f32 %0, %1, %2" : "=v"(u.i[3]) : "v"(b[2]), "v"(b[3]));
  return u.v;
}

// ---- prep: W1 -> Bf in MFMA-fragment order [cb20][ksg16][lane64][8] ----------
__global__ void moe_prep(const float* __restrict__ gw1, const float* __restrict__ aw1,
                         const float* __restrict__ bw1, unsigned short* __restrict__ Bf,
                         unsigned* __restrict__ cnt) {
  if (blockIdx.x == 0 && threadIdx.x == 0) *cnt = 0u;
  int idx = blockIdx.x * 512 + threadIdx.x;          // 320*512 = 163840
  int j = idx & 7, l = (idx >> 3) & 63, ks = (idx >> 9) & 15, cb = idx >> 13;
  int col = cb * 16 + (l & 15);
  int k = ks * 32 + ((l >> 4) << 3) + j;
  float v;
  if (col < 64)       v = gw1[k * 64 + col];
  else if (col < 192) v = aw1[k * 128 + (col - 64)];
  else                v = bw1[k * 128 + (col - 192)];
  Bf[idx] = f2bf(v);
}

// ---- main: 64 rows x 320 cols, 8 waves (2wr x 4wc), BK=32, 16 chunks ---------
// A: global -> regs -> cvt_pk -> MFMA (no LDS). B: 4-buffer LDS ring via
// global_load_lds, counted vmcnt (never 0 in steady state), ONE barrier/chunk.
__global__ __launch_bounds__(512, 4) void moe_main(
    const float* __restrict__ x, const unsigned short* __restrict__ Bf,
    const float* __restrict__ gb1, const float* __restrict__ gw2, const float* __restrict__ gb2,
    const float* __restrict__ ab1, const float* __restrict__ aw2, const float* __restrict__ ab2,
    const float* __restrict__ bb1, const float* __restrict__ bw2, const float* __restrict__ bb2,
    float* __restrict__ out, unsigned* __restrict__ cnt, unsigned* __restrict__ list, int cap) {
  __shared__ char L[81920];                   // 4 x 20KB B ring; part aliases buf0
  float* part = (float*)L;

  const int tid = threadIdx.x;
  const int w = tid >> 6, l = tid & 63;
  const int wr = w >> 2, wc = w & 3;          // 2 row-groups x 4 col-groups
  const int lo = l & 15, hi = l >> 4;
  const long br = (long)blockIdx.x * 64;

  // per-lane A base pointers (fragment-shaped: row = l&15, k-off = (l>>4)*8)
  const float* xb0 = x + (br + wr * 32 + lo) * 256 + hi * 8;
  const float* xb1 = xb0 + 16 * 256;

  // B DMA: 20 segments of 1KB per chunk, split [2,3,2,3,...] over 8 waves
  const int sb = (w * 20) >> 3, se = ((w + 1) * 20) >> 3;
  const unsigned short* bsrc = Bf + l * 8;

  f32x4 n0a, n0b, n1a, n1b;                   // A(kc+1) f32, in flight
  auto issueA = [&](int kc) {
    const long off = (long)(kc & 7) * 32 + (kc >= 8 ? (long)HALF_ROWS * 256 : 0L);
    const float* p0 = xb0 + off;
    const float* p1 = xb1 + off;
    n0a = *(const f32x4*)p0; n0b = *(const f32x4*)(p0 + 4);
    n1a = *(const f32x4*)p1; n1b = *(const f32x4*)(p1 + 4);
  };
  auto issueB = [&](int kc) {
    char* dst = L + (kc & 3) * 20480;
    const unsigned short* g = bsrc + kc * 512;
    for (int s = sb; s < se; ++s)
      GLOAD_LDS16(g + s * 8192, dst + s * 1024);
  };

  f32x4 acc0[5], acc1[5];
#pragma unroll
  for (int j = 0; j < 5; j++) {
    acc0[j] = (f32x4){0.f, 0.f, 0.f, 0.f};
    acc1[j] = (f32x4){0.f, 0.f, 0.f, 0.f};
  }

  issueA(0);                                  // order matters for vmcnt counting
  issueB(0);
  issueB(1);

#pragma unroll 1
  for (int kc = 0; kc < 16; ++kc) {
    // convert A(kc) (compiler waits only these 4 loads; B-DMAs stay in flight)
    s16x8 a0 = cvt8(n0a, n0b);
    s16x8 a1 = cvt8(n1a, n1b);
    asm volatile("" ::: "memory");
    if (kc < 15) issueA(kc + 1);              // next A into regs
    if (kc < 14) issueB(kc + 2);              // 2 B-chunks always in flight
    asm volatile("" ::: "memory");
    // drain A(kc)+B(kc) only: allowed = B(kc+1)[d] + A(kc+1)[4] + B(kc+2)[d]
    if (kc < 14)       { if (w & 1) WB(10); else WB(8); }
    else if (kc == 14) { if (w & 1) WB(7);  else WB(6); }
    else               { WB(0); }

    const char* buf = L + (kc & 3) * 20480;
#pragma unroll
    for (int ct = 0; ct < 5; ++ct) {
      s16x8 bf = *(const s16x8*)(buf + ((wc * 5 + ct) << 10) + (l << 4));
      acc0[ct] = __builtin_amdgcn_mfma_f32_16x16x32_bf16(a0, bf, acc0[ct], 0, 0, 0);
      acc1[ct] = __builtin_amdgcn_mfma_f32_16x16x32_bf16(a1, bf, acc1[ct], 0, 0, 0);
    }
  }

  // ---- epilogue: bias+relu+3 tiny heads; head uniform per (wc,ct) tile --------
  float b1v[5], w0v[5], w1v[5];
  int head[5];
#pragma unroll
  for (int ct = 0; ct < 5; ++ct) {
    int c0 = (wc * 5 + ct) * 16;
    int col = c0 + lo;
    int hd = c0 < 64 ? 0 : (c0 < 192 ? 1 : 2);
    head[ct] = hd;
    if (hd == 0)      { b1v[ct] = gb1[col];           w0v[ct] = gw2[col * 2];       w1v[ct] = gw2[col * 2 + 1]; }
    else if (hd == 1) { int c = col - 64;  b1v[ct] = ab1[c]; w0v[ct] = aw2[c * 2]; w1v[ct] = aw2[c * 2 + 1]; }
    else              { int c = col - 192; b1v[ct] = bb1[c]; w0v[ct] = bw2[c * 2]; w1v[ct] = bw2[c * 2 + 1]; }
  }

#define EPI(ACC, RT)                                                              \
  {                                                                               \
    float pg0[4] = {0,0,0,0}, pg1[4] = {0,0,0,0};                                 \
    float pa0[4] = {0,0,0,0}, pa1[4] = {0,0,0,0};                                 \
    float pq0[4] = {0,0,0,0}, pq1[4] = {0,0,0,0};                                 \
    _Pragma("unroll")                                                             \
    for (int ct = 0; ct < 5; ++ct)                                                \
      _Pragma("unroll")                                                           \
      for (int j = 0; j < 4; ++j) {                                               \
        float h = fmaxf(ACC[ct][j] + b1v[ct], 0.f);                               \
        float t0 = h * w0v[ct], t1 = h * w1v[ct];                                 \
        if (head[ct] == 0)      { pg0[j] += t0; pg1[j] += t1; }                   \
        else if (head[ct] == 1) { pa0[j] += t0; pa1[j] += t1; }                   \
        else                    { pq0[j] += t0; pq1[j] += t1; }                   \
      }                                                                           \
    _Pragma("unroll")                                                             \
    for (int m = 1; m < 16; m <<= 1)                                              \
      _Pragma("unroll")                                                           \
      for (int j = 0; j < 4; ++j) {                                               \
        pg0[j] += __shfl_xor(pg0[j], m); pg1[j] += __shfl_xor(pg1[j], m);         \
        pa0[j] += __shfl_xor(pa0[j], m); pa1[j] += __shfl_xor(pa1[j], m);         \
        pq0[j] += __shfl_xor(pq0[j], m); pq1[j] += __shfl_xor(pq1[j], m);         \
      }                                                                           \
    if (lo == 0) {                                                                \
      _Pragma("unroll")                                                           \
      for (int j = 0; j < 4; ++j) {                                               \
        int r = wr * 32 + (RT) * 16 + hi * 4 + j;                                 \
        float* pp = part + (r * 4 + wc) * 6;                                      \
        pp[0] = pg0[j]; pp[1] = pg1[j]; pp[2] = pa0[j];                           \
        pp[3] = pa1[j]; pp[4] = pq0[j]; pp[5] = pq1[j];                           \
      }                                                                           \
    }                                                                             \
  }

  // part aliases buf0: last read of buf0 was chunk 12, 3 barriers ago -> safe
  EPI(acc0, 0)
  EPI(acc1, 1)
  __syncthreads();

  if (tid < 64) {
    float g0 = 0, g1 = 0, a0 = 0, a1 = 0, e0 = 0, e1 = 0;
#pragma unroll
    for (int k2 = 0; k2 < 4; k2++) {
      float* pp = part + (tid * 4 + k2) * 6;
      g0 += pp[0]; g1 += pp[1]; a0 += pp[2]; a1 += pp[3]; e0 += pp[4]; e1 += pp[5];
    }
    float gl0 = g0 + gb2[0], gl1 = g1 + gb2[1];
    float fa0 = a0 + ab2[0], fa1 = a1 + ab2[1];
    float fb0 = e0 + bb2[0], fb1 = e1 + bb2[1];
    bool m0 = gl0 >= gl1;
    long grow = br + tid;
    f32x4 o;
    o[0] = m0 ? fa0 : 0.f; o[1] = m0 ? fa1 : 0.f;
    o[2] = m0 ? 0.f : fb0; o[3] = m0 ? 0.f : fb1;
    *(f32x4*)(out + grow * 4) = o;
    float diff = gl0 - gl1;
    if (fabsf(diff) < TAU && cap > 0) {
      unsigned u = atomicAdd(cnt, 1u);
      if (u < (unsigned)cap) {
        unsigned* e = list + (size_t)u * 8;
        e[0] = (unsigned)grow;
        float* ef = (float*)(e + 4);
        ef[0] = fa0; ef[1] = fa1; ef[2] = fb0; ef[3] = fb1;
      }
    }
  }
}

// ---- fixup: fp64 gate recompute for borderline rows --------------------------
__global__ void moe_fixup(const float* __restrict__ x,
                          const float* __restrict__ gw1, const float* __restrict__ gb1,
                          const float* __restrict__ gw2, const float* __restrict__ gb2,
                          float* __restrict__ out, const unsigned* __restrict__ cnt,
                          const unsigned* __restrict__ list, int cap) {
  unsigned n = *cnt;
  if (n > (unsigned)cap) n = (unsigned)cap;
  const int l = threadIdx.x & 63;
  const int wid = blockIdx.x * (blockDim.x >> 6) + (threadIdx.x >> 6);
  const int nw = gridDim.x * (blockDim.x >> 6);
  for (unsigned e = wid; e < n; e += nw) {
    const unsigned* ent = list + (size_t)e * 8;
    unsigned row = ent[0];
    const float* ef = (const float*)(ent + 4);
    const float* xr0 = x + (long)row * 256;
    const float* xr1 = x + ((long)row + HALF_ROWS) * 256;
    double a0 = 0.0, a1 = 0.0, a2 = 0.0, a3 = 0.0;
#pragma unroll 4
    for (int d = 0; d < 256; d += 4) {
      a0 += (double)xr0[d]     * (double)gw1[d * 64 + l];
      a1 += (double)xr0[d + 1] * (double)gw1[(d + 1) * 64 + l];
      a2 += (double)xr0[d + 2] * (double)gw1[(d + 2) * 64 + l];
      a3 += (double)xr0[d + 3] * (double)gw1[(d + 3) * 64 + l];
    }
#pragma unroll 4
    for (int d = 0; d < 256; d += 4) {
      a0 += (double)xr1[d]     * (double)gw1[(d + 256) * 64 + l];
      a1 += (double)xr1[d + 1] * (double)gw1[(d + 257) * 64 + l];
      a2 += (double)xr1[d + 2] * (double)gw1[(d + 258) * 64 + l];
      a3 += (double)xr1[d + 3] * (double)gw1[(d + 259) * 64 + l];
    }
    double h = a0 + a1 + a2 + a3 + (double)gb1[l];
    h = h > 0.0 ? h : 0.0;
    double t0 = h * (double)gw2[l * 2];
    double t1 = h * (double)gw2[l * 2 + 1];
#pragma unroll
    for (int m = 1; m < 64; m <<= 1) {
      t0 += __shfl_xor(t0, m);
      t1 += __shfl_xor(t1, m);
    }
    if (l == 0) {
      bool m0 = (t0 + (double)gb2[0]) >= (t1 + (double)gb2[1]);
      f32x4 o;
      o[0] = m0 ? ef[0] : 0.f; o[1] = m0 ? ef[1] : 0.f;
      o[2] = m0 ? 0.f : ef[2]; o[3] = m0 ? 0.f : ef[3];
      *(f32x4*)(out + (size_t)row * 4) = o;
    }
  }
}

extern "C" void kernel_launch(void* const* d_in, const int* in_sizes, int n_in,
                              void* d_out, int out_size, void* d_ws, size_t ws_size,
                              hipStream_t stream) {
  const float* x   = (const float*)d_in[0];
  const float* gw1 = (const float*)d_in[1];
  const float* gb1 = (const float*)d_in[2];
  const float* gw2 = (const float*)d_in[3];
  const float* gb2 = (const float*)d_in[4];
  const float* aw1 = (const float*)d_in[5];
  const float* ab1 = (const float*)d_in[6];
  const float* aw2 = (const float*)d_in[7];
  const float* ab2 = (const float*)d_in[8];
  const float* bw1 = (const float*)d_in[9];
  const float* bb1 = (const float*)d_in[10];
  const float* bw2 = (const float*)d_in[11];
  const float* bb2 = (const float*)d_in[12];
  float* out = (float*)d_out;

  unsigned char* ws = (unsigned char*)d_ws;
  unsigned* cnt = (unsigned*)ws;
  unsigned short* Bf = (unsigned short*)(ws + BT_OFF);
  unsigned* list = (unsigned*)(ws + LIST_OFF);
  long cap_l = ((long)ws_size - (long)LIST_OFF) / 32;
  int cap = cap_l < 0 ? 0 : (cap_l > 262144 ? 262144 : (int)cap_l);

  moe_prep<<<320, 512, 0, stream>>>(gw1, aw1, bw1, Bf, cnt);
  moe_main<<<4096, 512, 0, stream>>>(x, Bf, gb1, gw2, gb2, ab1, aw2, ab2,
                                     bb1, bw2, bb2, out, cnt, list, cap);
  moe_fixup<<<1024, 256, 0, stream>>>(x, gw1, gb1, gw2, gb2, out, cnt, list, cap);
}

// Round 9
// 329.457 us; speedup vs baseline: 1.2147x; 1.2147x over previous
//
#include <hip/hip_runtime.h>
#include <hip/hip_bf16.h>

#define HALF_ROWS 262144
#define TAU 0.04f
#define BT_OFF 1024
#define LIST_OFF (BT_OFF + 320 * 512 * 2)   // 1024 + 327680

typedef __attribute__((ext_vector_type(8))) short s16x8;
typedef __attribute__((ext_vector_type(4))) float f32x4;

__device__ __forceinline__ unsigned short f2bf(float f) {
  union { float f; unsigned u; } v; v.f = f;
  unsigned r = v.u + 0x7fffu + ((v.u >> 16) & 1u);   // RTNE
  return (unsigned short)(r >> 16);
}

#define GLOAD_LDS16(g, p) \
  __builtin_amdgcn_global_load_lds((const __attribute__((address_space(1))) void*)(g), \
                                   (__attribute__((address_space(3))) void*)(p), 16, 0, 0)

// 8 f32 -> one bf16x8 fragment via packed converts (RTNE)
__device__ __forceinline__ s16x8 cvt8(const f32x4& a, const f32x4& b) {
  union { int i[4]; s16x8 v; } u;
  asm("v_cvt_pk_bf16_f32 %0, %1, %2" : "=v"(u.i[0]) : "v"(a[0]), "v"(a[1]));
  asm("v_cvt_pk_bf16_f32 %0, %1, %2" : "=v"(u.i[1]) : "v"(a[2]), "v"(a[3]));
  asm("v_cvt_pk_bf16_f32 %0, %1, %2" : "=v"(u.i[2]) : "v"(b[0]), "v"(b[1]));
  asm("v_cvt_pk_bf16_f32 %0, %1, %2" : "=v"(u.i[3]) : "v"(b[2]), "v"(b[3]));
  return u.v;
}

// ---- prep: W1 -> Bf in MFMA-fragment order [cb20][ksg16][lane64][8] ----------
__global__ void moe_prep(const float* __restrict__ gw1, const float* __restrict__ aw1,
                         const float* __restrict__ bw1, unsigned short* __restrict__ Bf,
                         unsigned* __restrict__ cnt) {
  if (blockIdx.x == 0 && threadIdx.x == 0) *cnt = 0u;
  int idx = blockIdx.x * 512 + threadIdx.x;          // 320*512 = 163840
  int j = idx & 7, l = (idx >> 3) & 63, ks = (idx >> 9) & 15, cb = idx >> 13;
  int col = cb * 16 + (l & 15);
  int k = ks * 32 + ((l >> 4) << 3) + j;
  float v;
  if (col < 64)       v = gw1[k * 64 + col];
  else if (col < 192) v = aw1[k * 128 + (col - 64)];
  else                v = bw1[k * 128 + (col - 192)];
  Bf[idx] = f2bf(v);
}

// ---- main: BM=256, 1024 thr, 16 waves x (16 rows x 320 cols) -----------------
// A: frag-shaped global->reg->cvt (each row owned by ONE wave; crosses the CU
// port exactly once). B: 3-deep LDS ring via global_load_lds, 2 chunks ahead;
// compiler's counted wait for A drains exactly B(kc+1); one barrier/chunk.
__global__ __launch_bounds__(1024, 4) void moe_main(
    const float* __restrict__ x, const unsigned short* __restrict__ Bf,
    const float* __restrict__ gb1, const float* __restrict__ gw2, const float* __restrict__ gb2,
    const float* __restrict__ ab1, const float* __restrict__ aw2, const float* __restrict__ ab2,
    const float* __restrict__ bb1, const float* __restrict__ bw2, const float* __restrict__ bb2,
    float* __restrict__ out, unsigned* __restrict__ cnt, unsigned* __restrict__ list, int cap) {
  __shared__ char Bl[3][20480];               // 3 x 20KB B ring (BK=32)

  const int tid = threadIdx.x;
  const int w = tid >> 6, l = tid & 63;
  const int lo = l & 15, hi = l >> 4;
  const long row0 = (long)blockIdx.x * 256 + w * 16 + lo;   // this lane's A row
  const float* ap = x + row0 * 256 + hi * 8;

  // B DMA: seg cb -> 1KB; wave w does seg w, waves 0-3 also seg 16+w
  const unsigned short* bsrc = Bf + l * 8;
  auto issueB = [&](int kc) {
    char* dst = Bl[kc % 3];
    GLOAD_LDS16(bsrc + ((size_t)(w * 16 + kc) << 9), dst + w * 1024);
    if (w < 4)
      GLOAD_LDS16(bsrc + ((size_t)((16 + w) * 16 + kc) << 9), dst + (16 + w) * 1024);
  };

  f32x4 cur0, cur1, nxt0, nxt1;
  auto loadA = [&](int kc, f32x4& d0, f32x4& d1) {
    const float* p = ap + (kc & 7) * 32 + (kc >= 8 ? (long)HALF_ROWS * 256 : 0L);
    d0 = *(const f32x4*)p;
    d1 = *(const f32x4*)(p + 4);
  };

  f32x4 acc[20];
#pragma unroll
  for (int ct = 0; ct < 20; ++ct) acc[ct] = (f32x4){0.f, 0.f, 0.f, 0.f};

  // prologue: A(0), B(0), B(1); drain B(0); barrier
  loadA(0, cur0, cur1);
  issueB(0);
  issueB(1);
  if (w < 4) asm volatile("s_waitcnt vmcnt(2)" ::: "memory");
  else       asm volatile("s_waitcnt vmcnt(1)" ::: "memory");
  __builtin_amdgcn_s_barrier();

#pragma unroll 1
  for (int kc = 0; kc < 16; ++kc) {
    if (kc + 2 < 16) issueB(kc + 2);          // 2 ahead, stays in flight
    if (kc + 1 < 16) loadA(kc + 1, nxt0, nxt1);
    asm volatile("" ::: "memory");
    // cvt waits A(kc); since A(kc) was issued after B(kc+1), that wait also
    // drains B(kc+1) while keeping B(kc+2)+A(kc+1) outstanding.
    s16x8 af = cvt8(cur0, cur1);
    const char* buf = Bl[kc % 3];
#pragma unroll
    for (int ct = 0; ct < 20; ++ct) {
      s16x8 bf = *(const s16x8*)(buf + (ct << 10) + (l << 4));
      acc[ct] = __builtin_amdgcn_mfma_f32_16x16x32_bf16(af, bf, acc[ct], 0, 0, 0);
    }
    cur0 = nxt0; cur1 = nxt1;
    if (kc < 15) __builtin_amdgcn_s_barrier();
  }

  // ---- epilogue: wave-local (16 rows x all 320 cols) --------------------------
  float pg0[4] = {0,0,0,0}, pg1[4] = {0,0,0,0};
  float pa0[4] = {0,0,0,0}, pa1[4] = {0,0,0,0};
  float pq0[4] = {0,0,0,0}, pq1[4] = {0,0,0,0};
#pragma unroll
  for (int ct = 0; ct < 20; ++ct) {
    int col = ct * 16 + lo;
    float b1, w0, w1;
    if (ct < 4)       { b1 = gb1[col];        w0 = gw2[col * 2];        w1 = gw2[col * 2 + 1]; }
    else if (ct < 12) { int c = col - 64;  b1 = ab1[c]; w0 = aw2[c * 2]; w1 = aw2[c * 2 + 1]; }
    else              { int c = col - 192; b1 = bb1[c]; w0 = bw2[c * 2]; w1 = bw2[c * 2 + 1]; }
#pragma unroll
    for (int j = 0; j < 4; ++j) {
      float h = fmaxf(acc[ct][j] + b1, 0.f);
      float t0 = h * w0, t1 = h * w1;
      if (ct < 4)       { pg0[j] += t0; pg1[j] += t1; }
      else if (ct < 12) { pa0[j] += t0; pa1[j] += t1; }
      else              { pq0[j] += t0; pq1[j] += t1; }
    }
  }
#pragma unroll
  for (int m = 1; m < 16; m <<= 1)
#pragma unroll
    for (int j = 0; j < 4; ++j) {
      pg0[j] += __shfl_xor(pg0[j], m); pg1[j] += __shfl_xor(pg1[j], m);
      pa0[j] += __shfl_xor(pa0[j], m); pa1[j] += __shfl_xor(pa1[j], m);
      pq0[j] += __shfl_xor(pq0[j], m); pq1[j] += __shfl_xor(pq1[j], m);
    }
  if (lo == 0) {
    float g2a = gb2[0], g2b = gb2[1];
    float a2a = ab2[0], a2b = ab2[1];
    float b2a = bb2[0], b2b = bb2[1];
#pragma unroll
    for (int j = 0; j < 4; ++j) {
      long grow = ((long)blockIdx.x * 256 + w * 16) + hi * 4 + j;
      float gl0 = pg0[j] + g2a, gl1 = pg1[j] + g2b;
      float fa0 = pa0[j] + a2a, fa1 = pa1[j] + a2b;
      float fb0 = pq0[j] + b2a, fb1 = pq1[j] + b2b;
      bool m0 = gl0 >= gl1;
      f32x4 o;
      o[0] = m0 ? fa0 : 0.f; o[1] = m0 ? fa1 : 0.f;
      o[2] = m0 ? 0.f : fb0; o[3] = m0 ? 0.f : fb1;
      *(f32x4*)(out + grow * 4) = o;
      float diff = gl0 - gl1;
      if (fabsf(diff) < TAU && cap > 0) {
        unsigned u = atomicAdd(cnt, 1u);
        if (u < (unsigned)cap) {
          unsigned* e = list + (size_t)u * 8;
          e[0] = (unsigned)grow;
          float* ef = (float*)(e + 4);
          ef[0] = fa0; ef[1] = fa1; ef[2] = fb0; ef[3] = fb1;
        }
      }
    }
  }
}

// ---- fixup: fp64 gate recompute for borderline rows (8 ILP chains) -----------
__global__ void moe_fixup(const float* __restrict__ x,
                          const float* __restrict__ gw1, const float* __restrict__ gb1,
                          const float* __restrict__ gw2, const float* __restrict__ gb2,
                          float* __restrict__ out, const unsigned* __restrict__ cnt,
                          const unsigned* __restrict__ list, int cap) {
  unsigned n = *cnt;
  if (n > (unsigned)cap) n = (unsigned)cap;
  const int l = threadIdx.x & 63;
  const int wid = blockIdx.x * (blockDim.x >> 6) + (threadIdx.x >> 6);
  const int nw = gridDim.x * (blockDim.x >> 6);
  for (unsigned e = wid; e < n; e += nw) {
    const unsigned* ent = list + (size_t)e * 8;
    unsigned row = ent[0];
    const float* ef = (const float*)(ent + 4);
    const float* xr0 = x + (long)row * 256;
    const float* xr1 = x + ((long)row + HALF_ROWS) * 256;
    double a[8] = {0, 0, 0, 0, 0, 0, 0, 0};
#pragma unroll 2
    for (int d = 0; d < 256; d += 8)
#pragma unroll
      for (int q = 0; q < 8; ++q)
        a[q] += (double)xr0[d + q] * (double)gw1[(d + q) * 64 + l];
#pragma unroll 2
    for (int d = 0; d < 256; d += 8)
#pragma unroll
      for (int q = 0; q < 8; ++q)
        a[q] += (double)xr1[d + q] * (double)gw1[(d + 256 + q) * 64 + l];
    double h = ((a[0] + a[1]) + (a[2] + a[3])) + ((a[4] + a[5]) + (a[6] + a[7]))
             + (double)gb1[l];
    h = h > 0.0 ? h : 0.0;
    double t0 = h * (double)gw2[l * 2];
    double t1 = h * (double)gw2[l * 2 + 1];
#pragma unroll
    for (int m = 1; m < 64; m <<= 1) {
      t0 += __shfl_xor(t0, m);
      t1 += __shfl_xor(t1, m);
    }
    if (l == 0) {
      bool m0 = (t0 + (double)gb2[0]) >= (t1 + (double)gb2[1]);
      f32x4 o;
      o[0] = m0 ? ef[0] : 0.f; o[1] = m0 ? ef[1] : 0.f;
      o[2] = m0 ? 0.f : ef[2]; o[3] = m0 ? 0.f : ef[3];
      *(f32x4*)(out + (size_t)row * 4) = o;
    }
  }
}

extern "C" void kernel_launch(void* const* d_in, const int* in_sizes, int n_in,
                              void* d_out, int out_size, void* d_ws, size_t ws_size,
                              hipStream_t stream) {
  const float* x   = (const float*)d_in[0];
  const float* gw1 = (const float*)d_in[1];
  const float* gb1 = (const float*)d_in[2];
  const float* gw2 = (const float*)d_in[3];
  const float* gb2 = (const float*)d_in[4];
  const float* aw1 = (const float*)d_in[5];
  const float* ab1 = (const float*)d_in[6];
  const float* aw2 = (const float*)d_in[7];
  const float* ab2 = (const float*)d_in[8];
  const float* bw1 = (const float*)d_in[9];
  const float* bb1 = (const float*)d_in[10];
  const float* bw2 = (const float*)d_in[11];
  const float* bb2 = (const float*)d_in[12];
  float* out = (float*)d_out;

  unsigned char* ws = (unsigned char*)d_ws;
  unsigned* cnt = (unsigned*)ws;
  unsigned short* Bf = (unsigned short*)(ws + BT_OFF);
  unsigned* list = (unsigned*)(ws + LIST_OFF);
  long cap_l = ((long)ws_size - (long)LIST_OFF) / 32;
  int cap = cap_l < 0 ? 0 : (cap_l > 262144 ? 262144 : (int)cap_l);

  moe_prep<<<320, 512, 0, stream>>>(gw1, aw1, bw1, Bf, cnt);
  moe_main<<<1024, 1024, 0, stream>>>(x, Bf, gb1, gw2, gb2, ab1, aw2, ab2,
                                      bb1, bw2, bb2, out, cnt, list, cap);
  moe_fixup<<<2048, 256, 0, stream>>>(x, gw1, gb1, gw2, gb2, out, cnt, list, cap);
}